// Round 4
// baseline (7369.702 us; speedup 1.0000x reference)
//
#include <hip/hip_runtime.h>

#define T_SAVE 128
#define BT 8          // samples per block (half-tile; MFMA cols 8..15 are garbage lanes)
#define NTH 256       // 4 waves; each wave owns 2 chains of 16 features (32 of 128)

typedef __attribute__((ext_vector_type(8))) short short8;
typedef __attribute__((ext_vector_type(4))) float f32x4;
typedef unsigned int uint32;

// one-time weight convert: RTN-even
__device__ __forceinline__ short f2bf(float x) {
    union { float f; unsigned u; } v; v.f = x;
    return (short)((v.u + 0x7fffu + ((v.u >> 16) & 1u)) >> 16);
}
// activation path: round-half-up both halves, pack via v_perm_b32
__device__ __forceinline__ uint32 pack_bf2(float lo, float hi) {
    union { float f; uint32 u; } a, b; a.f = lo; b.f = hi;
    return __builtin_amdgcn_perm(b.u + 0x8000u, a.u + 0x8000u, 0x07060302u);
}
__device__ __forceinline__ float softplus_f(float x) {
    return fmaxf(x, 0.0f) + __logf(1.0f + __expf(-fabsf(x)));
}

static __device__ const float TA[5][5] = {
    {0.161f, 0.f, 0.f, 0.f, 0.f},
    {-0.008480655492356989f, 0.335480655492357f, 0.f, 0.f, 0.f},
    {2.8971530571054935f, -6.359448489975075f, 4.3622954328695815f, 0.f, 0.f},
    {5.325864828439257f, -11.748883564062828f, 7.4955393428898365f, -0.09249506636175525f, 0.f},
    {5.86145544294642f, -12.92096931784711f, 8.159367898576159f, -0.071584973281401f, -0.028269050394068383f}
};

__global__ __launch_bounds__(NTH, 2)
void node_mfma(const float* __restrict__ ts, const float* __restrict__ y0,
               const float* __restrict__ Win, const float* __restrict__ bin,
               const float* __restrict__ Wh, const float* __restrict__ bh,
               const float* __restrict__ Wout, const float* __restrict__ bout,
               float* __restrict__ out)
{
    // bf16 activation tiles [16 rows][136 stride]; rows 8..15 are garbage columns
    __shared__ __align__(16) short actA[16 * 136];
    __shared__ __align__(16) short actB[16 * 136];
    __shared__ __align__(16) short actC[16 * 136];
    // per-wave transpose scratch: 16 rows x 20 floats
    __shared__ __align__(16) float scr[4][320];

    const int tid  = threadIdx.x;
    const int wave = tid >> 6;
    const int lane = tid & 63;
    const int n    = lane & 15;          // MFMA row (weights) / col (sample)
    const int q    = lane >> 4;
    const int sn   = n & 7;              // clamped sample index for global loads
    const int s0   = blockIdx.x * BT;

    // per-chain feature bases: chain ch covers features 32*wave + 16*ch + [0,16)
    int rch[2], fbch[2];
    #pragma unroll
    for (int ch = 0; ch < 2; ++ch) {
        rch[ch]  = 32 * wave + 16 * ch + n;
        fbch[ch] = 32 * wave + 16 * ch + 4 * q;
    }

    // ---- weights as MFMA A-operand fragments ----
    short8 winf[2], whf[2][2][4], woutf[2][4];
    #pragma unroll
    for (int ch = 0; ch < 2; ++ch) {
        #pragma unroll
        for (int j = 0; j < 8; ++j) winf[ch][j] = f2bf(Win[rch[ch] * 32 + 8 * q + j]);
        #pragma unroll
        for (int c = 0; c < 4; ++c)
            #pragma unroll
            for (int j = 0; j < 8; ++j) {
                whf[0][ch][c][j] = f2bf(Wh[rch[ch] * 128 + 32 * c + 8 * q + j]);
                whf[1][ch][c][j] = f2bf(Wh[16384 + rch[ch] * 128 + 32 * c + 8 * q + j]);
                woutf[ch][c][j]  = f2bf(Wout[(16 * ch + n) * 128 + 32 * c + 8 * q + j]);
            }
    }
    float bin2[2][4], bh02[2][4], bh12[2][4], bo2[2][4];
    #pragma unroll
    for (int ch = 0; ch < 2; ++ch)
        #pragma unroll
        for (int rr = 0; rr < 4; ++rr) {
            bin2[ch][rr] = bin[fbch[ch] + rr];
            bh02[ch][rr] = bh[fbch[ch] + rr];
            bh12[ch][rr] = bh[128 + fbch[ch] + rr];
            bo2[ch][rr]  = bout[16 * ch + 4 * q + rr];
        }

    // ---- y state in registers (replicated per wave): yv[4*ch+rr] = dim 16*ch+4q+rr of sample n ----
    float yv[8];
    {
        f32x4 a = *(const f32x4*)&y0[(s0 + sn) * 32 + 4 * q];
        f32x4 b = *(const f32x4*)&y0[(s0 + sn) * 32 + 16 + 4 * q];
        #pragma unroll
        for (int rr = 0; rr < 4; ++rr) { yv[rr] = a[rr]; yv[4 + rr] = b[rr]; }
        if (wave == 0 && n < 8) {
            *(f32x4*)&out[(size_t)(s0 + n) * 4096 + 4 * q] = a;
            *(f32x4*)&out[(size_t)(s0 + n) * 4096 + 16 + 4 * q] = b;
        }
    }

    float kv[6][8];
    float* myscr = scr[wave];

    for (int ti = 0; ti < T_SAVE - 1; ++ti) {
        const float hsub = (ts[ti + 1] - ts[ti]) * 0.25f;
        #pragma unroll 1
        for (int sub = 0; sub < 4; ++sub) {
            #pragma unroll
            for (int st = 0; st < 6; ++st) {
                // ---- stage-y build (registers) ----
                float v[8];
                #pragma unroll
                for (int x = 0; x < 8; ++x) v[x] = yv[x];
                #pragma unroll
                for (int jj = 0; jj < 5; ++jj)
                    if (jj < st) {
                        const float c = hsub * TA[st - 1][jj];
                        #pragma unroll
                        for (int x = 0; x < 8; ++x) v[x] += c * kv[jj][x];
                    }
                uint2 lo, hi;
                lo.x = pack_bf2(v[0], v[1]); lo.y = pack_bf2(v[2], v[3]);
                hi.x = pack_bf2(v[4], v[5]); hi.y = pack_bf2(v[6], v[7]);
                // wave-private transpose (dims 16ch+4q+rr layout -> dims 8q..8q+7)
                *(uint2*)(myscr + n * 20 + 2 * q)     = lo;
                *(uint2*)(myscr + n * 20 + 8 + 2 * q) = hi;
                __asm__ volatile("s_waitcnt lgkmcnt(0)" ::: "memory");
                short8 bfrag = *(const short8*)((const short*)(myscr + n * 20 + 4 * q));

                // ---- input layer: 2 chains ----
                #pragma unroll
                for (int ch = 0; ch < 2; ++ch) {
                    f32x4 acc = {0.f, 0.f, 0.f, 0.f};
                    acc = __builtin_amdgcn_mfma_f32_16x16x32_bf16(winf[ch], bfrag, acc, 0, 0, 0);
                    float h0 = softplus_f(acc[0] + bin2[ch][0]);
                    float h1 = softplus_f(acc[1] + bin2[ch][1]);
                    float h2 = softplus_f(acc[2] + bin2[ch][2]);
                    float h3 = softplus_f(acc[3] + bin2[ch][3]);
                    uint2 pk; pk.x = pack_bf2(h0, h1); pk.y = pack_bf2(h2, h3);
                    *(uint2*)(actA + n * 136 + fbch[ch]) = pk;
                }
                __syncthreads();  // B1

                // ---- hidden 1: actA -> actB (read 4 chunks once, feed both chains) ----
                {
                    short8 bc[4];
                    #pragma unroll
                    for (int c = 0; c < 4; ++c)
                        bc[c] = *(const short8*)(actA + n * 136 + 32 * c + 8 * q);
                    #pragma unroll
                    for (int ch = 0; ch < 2; ++ch) {
                        f32x4 acc = {0.f, 0.f, 0.f, 0.f};
                        #pragma unroll
                        for (int c = 0; c < 4; ++c)
                            acc = __builtin_amdgcn_mfma_f32_16x16x32_bf16(whf[0][ch][c], bc[c], acc, 0, 0, 0);
                        float h0 = softplus_f(acc[0] + bh02[ch][0]);
                        float h1 = softplus_f(acc[1] + bh02[ch][1]);
                        float h2 = softplus_f(acc[2] + bh02[ch][2]);
                        float h3 = softplus_f(acc[3] + bh02[ch][3]);
                        uint2 pk; pk.x = pack_bf2(h0, h1); pk.y = pack_bf2(h2, h3);
                        *(uint2*)(actB + n * 136 + fbch[ch]) = pk;
                    }
                }
                __syncthreads();  // B2

                // ---- hidden 2: actB -> actC ----
                {
                    short8 bc[4];
                    #pragma unroll
                    for (int c = 0; c < 4; ++c)
                        bc[c] = *(const short8*)(actB + n * 136 + 32 * c + 8 * q);
                    #pragma unroll
                    for (int ch = 0; ch < 2; ++ch) {
                        f32x4 acc = {0.f, 0.f, 0.f, 0.f};
                        #pragma unroll
                        for (int c = 0; c < 4; ++c)
                            acc = __builtin_amdgcn_mfma_f32_16x16x32_bf16(whf[1][ch][c], bc[c], acc, 0, 0, 0);
                        float h0 = softplus_f(acc[0] + bh12[ch][0]);
                        float h1 = softplus_f(acc[1] + bh12[ch][1]);
                        float h2 = softplus_f(acc[2] + bh12[ch][2]);
                        float h3 = softplus_f(acc[3] + bh12[ch][3]);
                        uint2 pk; pk.x = pack_bf2(h0, h1); pk.y = pack_bf2(h2, h3);
                        *(uint2*)(actC + n * 136 + fbch[ch]) = pk;
                    }
                }
                __syncthreads();  // B3

                // ---- output layer: every wave computes all 32 dims (redundant, barrier-free k) ----
                {
                    short8 bc[4];
                    #pragma unroll
                    for (int c = 0; c < 4; ++c)
                        bc[c] = *(const short8*)(actC + n * 136 + 32 * c + 8 * q);
                    #pragma unroll
                    for (int ch = 0; ch < 2; ++ch) {
                        f32x4 oc = {0.f, 0.f, 0.f, 0.f};
                        #pragma unroll
                        for (int c = 0; c < 4; ++c)
                            oc = __builtin_amdgcn_mfma_f32_16x16x32_bf16(woutf[ch][c], bc[c], oc, 0, 0, 0);
                        #pragma unroll
                        for (int rr = 0; rr < 4; ++rr)
                            kv[st][4 * ch + rr] = oc[rr] + bo2[ch][rr];
                    }
                }
            }
            // ---- Tsit5 combine (registers, replicated) ----
            #pragma unroll
            for (int x = 0; x < 8; ++x)
                yv[x] += hsub * (0.09646076681806523f  * kv[0][x]
                               + 0.01f                 * kv[1][x]
                               + 0.4798896504144996f   * kv[2][x]
                               + 1.379008574103742f    * kv[3][x]
                               + (-3.290069515436081f) * kv[4][x]
                               + 2.324710524099774f    * kv[5][x]);
        }
        // ---- save point (wave 0, valid samples only) ----
        if (wave == 0 && n < 8) {
            f32x4 a, b;
            #pragma unroll
            for (int rr = 0; rr < 4; ++rr) { a[rr] = yv[rr]; b[rr] = yv[4 + rr]; }
            *(f32x4*)&out[(size_t)(s0 + n) * 4096 + (ti + 1) * 32 + 4 * q] = a;
            *(f32x4*)&out[(size_t)(s0 + n) * 4096 + (ti + 1) * 32 + 16 + 4 * q] = b;
        }
    }
}

extern "C" void kernel_launch(void* const* d_in, const int* in_sizes, int n_in,
                              void* d_out, int out_size, void* d_ws, size_t ws_size,
                              hipStream_t stream) {
    const float* ts   = (const float*)d_in[0];
    const float* y0   = (const float*)d_in[1];
    const float* Win  = (const float*)d_in[2];
    const float* bin  = (const float*)d_in[3];
    const float* Wh   = (const float*)d_in[4];
    const float* bh   = (const float*)d_in[5];
    const float* Wout = (const float*)d_in[6];
    const float* bout = (const float*)d_in[7];
    float* out = (float*)d_out;

    const int Btot = in_sizes[1] / 32;  // 4096 samples
    dim3 grid(Btot / BT), block(NTH);   // 512 blocks x 256 threads -> 2 blocks/CU
    node_mfma<<<grid, block, 0, stream>>>(ts, y0, Win, bin, Wh, bh, Wout, bout, out);
}

// Round 5
// 4475.354 us; speedup vs baseline: 1.6467x; 1.6467x over previous
//
#include <hip/hip_runtime.h>

#define T_SAVE 128
#define NTH 512

typedef __attribute__((ext_vector_type(8))) short short8;
typedef __attribute__((ext_vector_type(4))) float f32x4;
typedef unsigned int uint32;

__device__ __forceinline__ short f2bf(float x) {
    union { float f; unsigned u; } v; v.f = x;
    return (short)((v.u + 0x7fffu + ((v.u >> 16) & 1u)) >> 16);  // RTN-even
}
__device__ __forceinline__ float bf2f(short s) {
    union { unsigned u; float f; } v; v.u = ((unsigned)(unsigned short)s) << 16;
    return v.f;
}
__device__ __forceinline__ uint32 pack_bf2(float lo, float hi) {
    union { float f; uint32 u; } a, b; a.f = lo; b.f = hi;
    return __builtin_amdgcn_perm(b.u + 0x8000u, a.u + 0x8000u, 0x07060302u);
}
__device__ __forceinline__ float softplus_f(float x) {
    return fmaxf(x, 0.0f) + __logf(1.0f + __expf(-fabsf(x)));
}

static __device__ const float TA[5][5] = {
    {0.161f, 0.f, 0.f, 0.f, 0.f},
    {-0.008480655492356989f, 0.335480655492357f, 0.f, 0.f, 0.f},
    {2.8971530571054935f, -6.359448489975075f, 4.3622954328695815f, 0.f, 0.f},
    {5.325864828439257f, -11.748883564062828f, 7.4955393428898365f, -0.09249506636175525f, 0.f},
    {5.86145544294642f, -12.92096931784711f, 8.159367898576159f, -0.071584973281401f, -0.028269050394068383f}
};
static __device__ const float TB[6] = {
    0.09646076681806523f, 0.01f, 0.4798896504144996f,
    1.379008574103742f, -3.290069515436081f, 2.324710524099774f
};

__global__ __launch_bounds__(NTH, 2)
void node_mfma(const float* __restrict__ ts, const float* __restrict__ y0,
               const float* __restrict__ Win, const float* __restrict__ bin,
               const float* __restrict__ Wh, const float* __restrict__ bh,
               const float* __restrict__ Wout, const float* __restrict__ bout,
               float* __restrict__ out)
{
    __shared__ __align__(16) short actA[16 * 136];
    __shared__ __align__(16) short actB[16 * 136];
    __shared__ __align__(16) short actC[16 * 136];
    __shared__ __align__(16) float haccL[16 * 132];   // fp32 Hacc staging

    const int tid  = threadIdx.x;
    const int wave = tid >> 6;
    const int lane = tid & 63;
    const int n    = lane & 15;
    const int q    = lane >> 4;
    const int r    = 16 * wave + n;       // A-frag matrix row (feature)
    const int fb   = 16 * wave + 4 * q;   // features this lane's D rows cover
    const int s0   = blockIdx.x * 16;

    // ---- hidden weight fragments ----
    short8 whf0[4], whf1[4];
    #pragma unroll
    for (int c = 0; c < 4; ++c)
        #pragma unroll
        for (int j = 0; j < 8; ++j) {
            whf0[c][j] = f2bf(Wh[r * 128 + 32 * c + 8 * q + j]);
            whf1[c][j] = f2bf(Wh[16384 + r * 128 + 32 * c + 8 * q + j]);
        }

    // ---- F = Win·Wout fragments, fp32 accumulate then round (once) ----
    short8 ff[4];
    {
        float wrow[32];
        #pragma unroll
        for (int i = 0; i < 8; ++i) *(f32x4*)&wrow[4 * i] = *(const f32x4*)&Win[r * 32 + 4 * i];
        #pragma unroll 1
        for (int c = 0; c < 4; ++c) {
            float facc[8] = {0, 0, 0, 0, 0, 0, 0, 0};
            #pragma unroll
            for (int d = 0; d < 32; ++d) {
                f32x4 wa = *(const f32x4*)&Wout[d * 128 + 32 * c + 8 * q];
                f32x4 wb = *(const f32x4*)&Wout[d * 128 + 32 * c + 8 * q + 4];
                #pragma unroll
                for (int j = 0; j < 4; ++j) { facc[j] += wrow[d] * wa[j]; facc[4 + j] += wrow[d] * wb[j]; }
            }
            #pragma unroll
            for (int j = 0; j < 8; ++j) ff[c][j] = f2bf(facc[j]);
        }
    }

    // ---- c4 = (Win·bout)[fb+rr];  Yb = Win·y0[n] + bin (projected state) ----
    float c4v[4], Yb[4];
    #pragma unroll
    for (int rr = 0; rr < 4; ++rr) {
        const float* wr = &Win[(fb + rr) * 32];
        const float* yr = &y0[(size_t)(s0 + n) * 32];
        float cb = 0.f, yb = 0.f;
        #pragma unroll
        for (int d = 0; d < 32; ++d) { float w = wr[d]; cb += w * bout[d]; yb += w * yr[d]; }
        c4v[rr] = cb;
        Yb[rr]  = yb + bin[fb + rr];
    }
    float bh04[4], bh14[4];
    #pragma unroll
    for (int rr = 0; rr < 4; ++rr) { bh04[rr] = bh[fb + rr]; bh14[rr] = bh[128 + fb + rr]; }

    // ---- exact y (wave 0 only), dims 4q+rr / 16+4q+rr of sample n ----
    float yA[4], yB[4], boA[4], boB[4];
    if (wave == 0) {
        f32x4 a = *(const f32x4*)&y0[(size_t)(s0 + n) * 32 + 4 * q];
        f32x4 b = *(const f32x4*)&y0[(size_t)(s0 + n) * 32 + 16 + 4 * q];
        #pragma unroll
        for (int rr = 0; rr < 4; ++rr) {
            yA[rr] = a[rr]; yB[rr] = b[rr];
            boA[rr] = bout[4 * q + rr]; boB[rr] = bout[16 + 4 * q + rr];
        }
        *(f32x4*)&out[(size_t)(s0 + n) * 4096 + 4 * q] = a;
        *(f32x4*)&out[(size_t)(s0 + n) * 4096 + 16 + 4 * q] = b;
    }

    float zv[6][4];

    #pragma unroll 1
    for (int ti = 0; ti < T_SAVE - 1; ++ti) {
        const float hsub = (ts[ti + 1] - ts[ti]) * 0.25f;
        float Hacc[4] = {0.f, 0.f, 0.f, 0.f};
        #pragma unroll 1
        for (int sub = 0; sub < 4; ++sub) {
            #pragma unroll
            for (int st = 0; st < 6; ++st) {
                // ---- u = Yb + h*sum(a_j z_j); softplus; write actA ----
                float u[4];
                #pragma unroll
                for (int rr = 0; rr < 4; ++rr) u[rr] = Yb[rr];
                #pragma unroll
                for (int jj = 0; jj < 5; ++jj)
                    if (jj < st) {
                        const float cc = hsub * TA[st - 1][jj];
                        #pragma unroll
                        for (int rr = 0; rr < 4; ++rr) u[rr] += cc * zv[jj][rr];
                    }
                {
                    float h0 = softplus_f(u[0]), h1 = softplus_f(u[1]);
                    float h2 = softplus_f(u[2]), h3 = softplus_f(u[3]);
                    uint2 pk; pk.x = pack_bf2(h0, h1); pk.y = pack_bf2(h2, h3);
                    *(uint2*)(actA + n * 136 + fb) = pk;
                }
                __syncthreads();  // B1

                // ---- hidden 1: actA -> actB ----
                {
                    f32x4 acc = {0.f, 0.f, 0.f, 0.f};
                    #pragma unroll
                    for (int c = 0; c < 4; ++c) {
                        short8 b = *(const short8*)(actA + n * 136 + 32 * c + 8 * q);
                        acc = __builtin_amdgcn_mfma_f32_16x16x32_bf16(whf0[c], b, acc, 0, 0, 0);
                    }
                    float h0 = softplus_f(acc[0] + bh04[0]);
                    float h1 = softplus_f(acc[1] + bh04[1]);
                    float h2 = softplus_f(acc[2] + bh04[2]);
                    float h3 = softplus_f(acc[3] + bh04[3]);
                    uint2 pk; pk.x = pack_bf2(h0, h1); pk.y = pack_bf2(h2, h3);
                    *(uint2*)(actB + n * 136 + fb) = pk;
                }
                __syncthreads();  // B2

                // ---- hidden 2: actB -> actC; accumulate Hacc (fp32 h3) ----
                {
                    f32x4 acc = {0.f, 0.f, 0.f, 0.f};
                    #pragma unroll
                    for (int c = 0; c < 4; ++c) {
                        short8 b = *(const short8*)(actB + n * 136 + 32 * c + 8 * q);
                        acc = __builtin_amdgcn_mfma_f32_16x16x32_bf16(whf1[c], b, acc, 0, 0, 0);
                    }
                    float h3f[4];
                    #pragma unroll
                    for (int rr = 0; rr < 4; ++rr) h3f[rr] = softplus_f(acc[rr] + bh14[rr]);
                    const float hb = hsub * TB[st];
                    #pragma unroll
                    for (int rr = 0; rr < 4; ++rr) Hacc[rr] += hb * h3f[rr];
                    uint2 pk; pk.x = pack_bf2(h3f[0], h3f[1]); pk.y = pack_bf2(h3f[2], h3f[3]);
                    *(uint2*)(actC + n * 136 + fb) = pk;
                }
                __syncthreads();  // B3

                // ---- fused layer: z_st = F·h3 + c  (non-redundant, registers) ----
                {
                    f32x4 acc = {0.f, 0.f, 0.f, 0.f};
                    #pragma unroll
                    for (int c = 0; c < 4; ++c) {
                        short8 b = *(const short8*)(actC + n * 136 + 32 * c + 8 * q);
                        acc = __builtin_amdgcn_mfma_f32_16x16x32_bf16(ff[c], b, acc, 0, 0, 0);
                    }
                    #pragma unroll
                    for (int rr = 0; rr < 4; ++rr) zv[st][rr] = acc[rr] + c4v[rr];
                }
            }
            // ---- projected-state combine: Yb += h*sum(b_j z_j) ----
            #pragma unroll
            for (int rr = 0; rr < 4; ++rr)
                Yb[rr] += hsub * (TB[0] * zv[0][rr] + TB[1] * zv[1][rr] + TB[2] * zv[2][rr]
                                + TB[3] * zv[3][rr] + TB[4] * zv[4][rr] + TB[5] * zv[5][rr]);
        }

        // ---- interval end: y += Wout·Hacc_total + 4h·bout (wave 0, hi/lo exact) ----
        {
            f32x4 hv; hv[0] = Hacc[0]; hv[1] = Hacc[1]; hv[2] = Hacc[2]; hv[3] = Hacc[3];
            *(f32x4*)(haccL + n * 132 + fb) = hv;
        }
        __syncthreads();
        if (wave == 0) {
            f32x4 d0 = {0.f, 0.f, 0.f, 0.f};
            f32x4 d1 = {0.f, 0.f, 0.f, 0.f};
            #pragma unroll
            for (int c = 0; c < 4; ++c) {
                f32x4 ha = *(const f32x4*)(haccL + n * 132 + 32 * c + 8 * q);
                f32x4 hb2 = *(const f32x4*)(haccL + n * 132 + 32 * c + 8 * q + 4);
                short8 Hhi, Hlo;
                #pragma unroll
                for (int j = 0; j < 4; ++j) {
                    short h = f2bf(ha[j]);  Hhi[j] = h;     Hlo[j] = f2bf(ha[j] - bf2f(h));
                    short g = f2bf(hb2[j]); Hhi[4 + j] = g; Hlo[4 + j] = f2bf(hb2[j] - bf2f(g));
                }
                #pragma unroll
                for (int ch = 0; ch < 2; ++ch) {
                    f32x4 wa = *(const f32x4*)&Wout[(16 * ch + n) * 128 + 32 * c + 8 * q];
                    f32x4 wb = *(const f32x4*)&Wout[(16 * ch + n) * 128 + 32 * c + 8 * q + 4];
                    short8 Whi, Wlo;
                    #pragma unroll
                    for (int j = 0; j < 4; ++j) {
                        short h = f2bf(wa[j]); Whi[j] = h;     Wlo[j] = f2bf(wa[j] - bf2f(h));
                        short g = f2bf(wb[j]); Whi[4 + j] = g; Wlo[4 + j] = f2bf(wb[j] - bf2f(g));
                    }
                    f32x4 dd = ch ? d1 : d0;
                    dd = __builtin_amdgcn_mfma_f32_16x16x32_bf16(Whi, Hhi, dd, 0, 0, 0);
                    dd = __builtin_amdgcn_mfma_f32_16x16x32_bf16(Whi, Hlo, dd, 0, 0, 0);
                    dd = __builtin_amdgcn_mfma_f32_16x16x32_bf16(Wlo, Hhi, dd, 0, 0, 0);
                    if (ch) d1 = dd; else d0 = dd;
                }
            }
            const float hb4 = 4.f * hsub;
            f32x4 oa, ob;
            #pragma unroll
            for (int rr = 0; rr < 4; ++rr) {
                yA[rr] += d0[rr] + hb4 * boA[rr];
                yB[rr] += d1[rr] + hb4 * boB[rr];
                oa[rr] = yA[rr]; ob[rr] = yB[rr];
            }
            *(f32x4*)&out[(size_t)(s0 + n) * 4096 + (ti + 1) * 32 + 4 * q] = oa;
            *(f32x4*)&out[(size_t)(s0 + n) * 4096 + (ti + 1) * 32 + 16 + 4 * q] = ob;
        }
    }
}

extern "C" void kernel_launch(void* const* d_in, const int* in_sizes, int n_in,
                              void* d_out, int out_size, void* d_ws, size_t ws_size,
                              hipStream_t stream) {
    const float* ts   = (const float*)d_in[0];
    const float* y0   = (const float*)d_in[1];
    const float* Win  = (const float*)d_in[2];
    const float* bin  = (const float*)d_in[3];
    const float* Wh   = (const float*)d_in[4];
    const float* bh   = (const float*)d_in[5];
    const float* Wout = (const float*)d_in[6];
    const float* bout = (const float*)d_in[7];
    float* out = (float*)d_out;

    const int Btot = in_sizes[1] / 32;  // 4096 samples
    dim3 grid(Btot / 16), block(NTH);   // 256 blocks x 512 threads, 1 block/CU
    node_mfma<<<grid, block, 0, stream>>>(ts, y0, Win, bin, Wh, bh, Wout, bout, out);
}